// Round 1
// baseline (427.633 us; speedup 1.0000x reference)
//
#include <hip/hip_runtime.h>

// Row-wise softmax: out = exp(x) / sum(exp(x), axis=-1)
// x: (16384, 4096) fp32. One block per row, 256 threads, 16 elems/thread
// held in registers -> single global read + single global write per element.

constexpr int COLS = 4096;
constexpr int THREADS = 256;
constexpr int VEC = 4;                          // float4
constexpr int PER_THREAD = COLS / (THREADS * VEC); // 4 float4 per thread

__global__ __launch_bounds__(THREADS) void softmax_rows_kernel(
    const float* __restrict__ x, float* __restrict__ out) {
  const long long row = blockIdx.x;
  const float4* __restrict__ xin =
      reinterpret_cast<const float4*>(x + row * COLS);
  float4* __restrict__ xout = reinterpret_cast<float4*>(out + row * COLS);

  const int tid = threadIdx.x;

  float4 e[PER_THREAD];
  float local = 0.0f;
#pragma unroll
  for (int k = 0; k < PER_THREAD; ++k) {
    float4 v = xin[tid + k * THREADS];
    e[k].x = __expf(v.x);
    e[k].y = __expf(v.y);
    e[k].z = __expf(v.z);
    e[k].w = __expf(v.w);
    local += (e[k].x + e[k].y) + (e[k].z + e[k].w);
  }

  // Wave (64-lane) shuffle reduction
#pragma unroll
  for (int off = 32; off > 0; off >>= 1)
    local += __shfl_down(local, off, 64);

  __shared__ float wsum[THREADS / 64];
  const int lane = tid & 63;
  const int wave = tid >> 6;
  if (lane == 0) wsum[wave] = local;
  __syncthreads();

  const float total = (wsum[0] + wsum[1]) + (wsum[2] + wsum[3]);
  const float inv = 1.0f / total;

#pragma unroll
  for (int k = 0; k < PER_THREAD; ++k) {
    float4 o;
    o.x = e[k].x * inv;
    o.y = e[k].y * inv;
    o.z = e[k].z * inv;
    o.w = e[k].w * inv;
    xout[tid + k * THREADS] = o;
  }
}

extern "C" void kernel_launch(void* const* d_in, const int* in_sizes, int n_in,
                              void* d_out, int out_size, void* d_ws,
                              size_t ws_size, hipStream_t stream) {
  const float* x = (const float*)d_in[0];
  float* out = (float*)d_out;
  const int rows = in_sizes[0] / COLS;  // 16384
  softmax_rows_kernel<<<rows, THREADS, 0, stream>>>(x, out);
}